// Round 5
// baseline (12.214 us; speedup 1.0000x reference)
//
#include <hip/hip_runtime.h>

// WavetableModel: out[n] = sum_t exp(log_norm - 0.5*z^2) * table[t] / (peak+1e-8)
//   z=(t/4095-mu)/sigma, mu=frac((n+1)*|f0|), sigma=0.01+1e-8.
// Fully exp-free, LDS-read-minimal inner loop.
//   weight(k+q) = [rk*g_k] * (r1*t_k)^q * C_q,  q=0..3   (C_q=exp(-dz^2 q^2/2))
//   chunk stride 32 taps: rk*=R32(sample exp), t*=T32, g*=m, m*=MD (consts)
// Window +-128 taps (3.125 sigma): truncation <=~0.09 abs vs threshold 2.05.
// Staging: global_load_lds width=16 (linear LDS dest), zero-pad 128 floats.
// Model: ~7.4us fixed graph/launch overhead; LDS-issue is exec bottleneck.

#define NS     32768
#define TS     4096
#define BLK    256
#define LPS    8                 // lanes per sample
#define SPB    (BLK / LPS)       // 32 samples per block
#define NBLK   (NS / SPB)        // 1024 blocks
#define HALF   128               // half-window in taps
#define NCHUNK 64                // float4 chunks per sample (256 taps)
#define TPAD   4224              // 4096 + 128 pad; max read 3964+255=4219

__global__ __launch_bounds__(BLK) void wt_kernel(const float* __restrict__ f0p,
                                                 const float* __restrict__ table,
                                                 float* __restrict__ out)
{
    __shared__ __align__(16) float tab[TPAD];
    const int tid  = threadIdx.x;
    const int wave = tid >> 6;
    const int lane = tid & 63;

    // ---- constants (compile-time) ----
    constexpr double SIGMA   = 0.01 + 1e-8;
    constexpr double INV_SG  = 1.0 / SIGMA;
    constexpr double DZ      = 1.0 / (4095.0 * SIGMA);   // z step per tap
    constexpr double DZ2     = DZ * DZ;
    const float log_norm = 3.6862306527839187f;          // -ln(sigma)-0.5*ln(2pi)
    const float C1 = (float)exp(-0.5 * DZ2 * 1.0);
    const float C2 = (float)exp(-0.5 * DZ2 * 4.0);
    const float C3 = (float)exp(-0.5 * DZ2 * 9.0);
    const float T32 = (float)exp(-32.0 * DZ2);           // t stride factor
    const float MD  = (float)exp(-1024.0 * DZ2);         // m stride factor

    // ---- stage table -> LDS via global_load_lds (1024 float4, linear) ----
    {
        const float4* t4 = (const float4*)table;
        #pragma unroll
        for (int it = 0; it < 4; ++it) {
            const int f = it * 256 + wave * 64;          // wave-uniform float4 base
            __builtin_amdgcn_global_load_lds(
                (const __attribute__((address_space(1))) void*)(t4 + f + lane),
                (__attribute__((address_space(3))) void*)(tab + 4 * f),
                16, 0, 0);
        }
        if (tid < (TPAD - TS) / 4)
            ((float4*)tab)[TS / 4 + tid] = make_float4(0.f, 0.f, 0.f, 0.f);
    }
    const float f0a = fabsf(f0p[0]);
    __syncthreads();

    const int g = blockIdx.x * BLK + tid;
    const int n = g >> 3;        // sample index
    const int j = g & (LPS - 1); // lane-within-sample

    // mu exactly (double): frac((n+1)*|f0|)
    const double mu = fmod((double)(n + 1) * (double)f0a, 1.0);

    // normalizer: window value at nearest grid point
    const int tc = (int)(mu * 4095.0 + 0.5);
    const float zsf = (float)(((double)tc * (1.0 / 4095.0) - mu) * INV_SG);
    const float peak = __expf(fmaf(-0.5f * zsf, zsf, log_norm));
    const float denom = peak + 1e-8f;

    int t0 = tc - HALF;
    t0 = (t0 < 0) ? 0 : t0;
    t0 &= ~3;                    // float4 alignment

    const double z0d = ((double)t0 * (1.0 / 4095.0) - mu) * INV_SG;
    const float  z0  = (float)z0d;
    const float  bb  = (float)(-z0d * DZ);               // ln R (per-tap log-step)

    const float e0  = __expf(fmaf(-0.5f * z0, z0, log_norm));
    const float r1  = __expf(bb);
    const float R32 = __expf(bb * 32.0f);
    const float k0f = (float)(4 * j);                    // lane start tap
    float rk = __expf(bb * k0f);                         // exp(bb*k0)
    // per-lane const seeds (k = k0): t=exp(-DZ2*k), g=exp(-DZ2*k^2/2),
    // m=exp(-32*DZ2*k - 512*DZ2)
    float tch = __expf((float)(-DZ2) * k0f);
    float gch = __expf((float)(-0.5 * DZ2) * k0f * k0f);
    float mch = __expf((float)(-32.0 * DZ2) * k0f + (float)(-512.0 * DZ2));

    const float4* __restrict__ src = (const float4*)(tab + t0);
    float acc = 0.f;
    #pragma unroll
    for (int c = j; c < NCHUNK; c += LPS) {   // 8 chunks per lane, stride 32 taps
        const float4 v = src[c];
        const float A  = rk * gch;            // rk * g_k
        const float s  = r1 * tch;            // per-tap ratio at this k
        const float s2 = s * s;
        const float s3 = s2 * s;
        acc = fmaf(A,            v.x, acc);
        acc = fmaf(A * s  * C1,  v.y, acc);
        acc = fmaf(A * s2 * C2,  v.z, acc);
        acc = fmaf(A * s3 * C3,  v.w, acc);
        rk  *= R32;
        gch *= mch;
        mch *= MD;
        tch *= T32;
    }

    // reduce 8 lanes -> sample
    acc += __shfl_xor(acc, 1);
    acc += __shfl_xor(acc, 2);
    acc += __shfl_xor(acc, 4);
    if (j == 0) out[n] = acc * e0 / denom;
}

extern "C" void kernel_launch(void* const* d_in, const int* in_sizes, int n_in,
                              void* d_out, int out_size, void* d_ws, size_t ws_size,
                              hipStream_t stream)
{
    const float* f0    = (const float*)d_in[1];   // d_in[0] = x (unused by the math)
    const float* table = (const float*)d_in[2];
    float* out = (float*)d_out;
    wt_kernel<<<dim3(NBLK), dim3(BLK), 0, stream>>>(f0, table, out);
}